// Round 7
// baseline (1101.594 us; speedup 1.0000x reference)
//
#include <hip/hip_runtime.h>
#include <math.h>

#define NPTS 4096
#define DIM 64
#define LOGW2 (-12.0f)               // -log2(4096)  (log-domain is base-2)
#define NEGINF (-__builtin_inff())

typedef __bf16 bf16x8 __attribute__((ext_vector_type(8)));
typedef float f32x4 __attribute__((ext_vector_type(4)));

static __device__ __forceinline__ f32x4 mfma16(bf16x8 a, bf16x8 b, f32x4 c) {
  return __builtin_amdgcn_mfma_f32_16x16x32_bf16(a, b, c, 0, 0, 0);
}
// raw hardware base-2 transcendentals (v_exp_f32 / v_log_f32)
static __device__ __forceinline__ float exp2v(float x) {
  return __builtin_amdgcn_exp2f(x);
}
static __device__ __forceinline__ float log2v(float x) {
  return __builtin_amdgcn_logf(x);
}

// ---------------------------------------------------------------------------
// Normalize rows to unit L2 norm, split into bf16 hi/lo, and REPACK into the
// MFMA fragment-tile layout so the GEMM kernel's loads are lane-contiguous:
//   tile t (16 rows), chunk c in {0,1}, lane L = quad*16 + mrow:
//     offset(t,c,L,j) = t*1024 + c*512 + L*8 + j    (bf16 elements, j<8)
//     holds element [row = t*16 + mrow][k = c*32 + quad*8 + j].
// A-frag and B-frag (B^T GEMM) use the SAME layout -> one copy serves both.
// grid 256 x 256 thr; block = 32 rows (2 tiles) of x or y, via LDS transpose.
// ---------------------------------------------------------------------------
__global__ __launch_bounds__(256) void norm_repack_kernel(
    const float* __restrict__ x, const float* __restrict__ y,
    __bf16* __restrict__ xhf, __bf16* __restrict__ xlf,
    __bf16* __restrict__ yhf, __bf16* __restrict__ ylf) {
  __shared__ float tf[32][72];       // +8 pad: 16B-aligned rows, bank-spread
  int r0 = blockIdx.x * 32;
  const float* src;
  __bf16 *dh, *dl;
  int rbase;
  if (r0 < NPTS) { src = x; dh = xhf; dl = xlf; rbase = r0; }
  else           { src = y; dh = yhf; dl = ylf; rbase = r0 - NPTS; }

  int wave = threadIdx.x >> 6, lane = threadIdx.x & 63;
  #pragma unroll
  for (int i = 0; i < 8; ++i) {
    int wrow = wave * 8 + i;
    float v = src[(size_t)(rbase + wrow) * DIM + lane];
    float s = v * v;
    #pragma unroll
    for (int o = 32; o; o >>= 1) s += __shfl_xor(s, o, 64);
    tf[wrow][lane] = v * (1.0f / sqrtf(s));
  }
  __syncthreads();

  int tt   = threadIdx.x >> 7;        // tile within block (0/1)
  int idx  = threadIdx.x & 127;
  int c    = idx >> 6, L = idx & 63;
  int quad = L >> 4, mrow = L & 15;
  const float* rp = &tf[tt * 16 + mrow][c * 32 + quad * 8];
  bf16x8 hv, lv;
  #pragma unroll
  for (int j = 0; j < 8; ++j) {
    float v = rp[j];
    __bf16 h = (__bf16)v;
    hv[j] = h;
    lv[j] = (__bf16)(v - (float)h);
  }
  size_t ob = (size_t)(rbase / 16 + tt) * 1024 + c * 512 + L * 8;
  *(bf16x8*)(dh + ob) = hv;           // fully coalesced 16B/lane writes
  *(bf16x8*)(dl + ob) = lv;
}

// ---------------------------------------------------------------------------
// FUSED sweep (v5): recompute cost tiles via split-bf16 MFMA from the
// fragment-tile layout, feed fp32 accumulators straight into an online
// row-logsumexp in the base-2 log domain.
//
// Round-6 lesson: MfmaUtil 23 + VALUBusy 46, occupancy 18.7% -- issue-bound
// with only 2 waves/SIMD (grid = 1 block/CU) at 88 VGPR, which allows 4.
// Now: 1024-thread blocks (16 waves, wave owns 256 cols = 8 pairs), same
// grid of 256 blocks, same per-wave structure and B traffic -> 4 waves/SIMD
// so MFMA and VALU pipes overlap across waves. B loads go through
// wave-uniform bumped pointers -> saddr-form loads, no per-lane 64b addr math.
//
// Block = 64 rows x 4096 cols; 6 MFMA per 16x16 tile (hi.hi + lo.hi + hi.lo).
// C/D frag: col = L&15 (= h index), row = (L>>4)*4 + q within the row-set.
// tv = h2_j - cost*inv_eps2 = fma(min(dot,1), inv_eps2, h2_j - inv_eps2).
// 2-element blocked LSE (same (quad,q) slot of consecutive tiles = same row).
// Merge: shfl over 16 col-lanes, then LDS merge across 16 waves.
// Final: ft = -eps*ln(sum) = -(eps*ln2)*(m + log2(s)).
// ---------------------------------------------------------------------------
__global__ __launch_bounds__(1024, 4) void fused_pass_kernel(
    const __bf16* __restrict__ xhf, const __bf16* __restrict__ xlf,
    const __bf16* __restrict__ yhf, const __bf16* __restrict__ ylf,
    const float* __restrict__ potOld, float* __restrict__ potNew,
    float inv_eps2, float epsl2, int use_pot, int avg) {
  __shared__ float hlds[NPTS];       // 16 KB: h2[j] = -12 + pot[j]*inv_eps2
  __shared__ float mred[16][64];
  __shared__ float sred[16][64];

  int mat = blockIdx.x >> 6;
  int rb  = blockIdx.x & 63;
  const __bf16 *Ah, *Al, *Bh, *Bl;
  if (mat == 0)      { Ah = xhf; Al = xlf; Bh = yhf; Bl = ylf; }
  else if (mat == 1) { Ah = yhf; Al = ylf; Bh = xhf; Bl = xlf; }
  else if (mat == 2) { Ah = xhf; Al = xlf; Bh = xhf; Bl = xlf; }
  else               { Ah = yhf; Al = ylf; Bh = yhf; Bl = ylf; }
  int ridx = (mat == 0) ? 1 : ((mat == 1) ? 0 : mat);
  const float* pot = potOld + (size_t)ridx * NPTS;

  // stage h2[] into LDS: 1024 thr x 4 floats
  {
    int j4 = threadIdx.x * 4;
    float4 p;
    if (use_pot) {
      float4 q = *(const float4*)(pot + j4);
      p.x = fmaf(q.x, inv_eps2, LOGW2); p.y = fmaf(q.y, inv_eps2, LOGW2);
      p.z = fmaf(q.z, inv_eps2, LOGW2); p.w = fmaf(q.w, inv_eps2, LOGW2);
    } else {
      p.x = p.y = p.z = p.w = LOGW2;
    }
    *(float4*)(hlds + j4) = p;
  }
  __syncthreads();

  int wave = threadIdx.x >> 6, L = threadIdx.x & 63;
  int mrow = L & 15, quad = L >> 4;
  int lofs = L * 8;
  int i0 = rb * 64;

  // A fragments: 4 row-sets (tiles rb*4 .. rb*4+3), 64 VGPR
  bf16x8 Ah0[4], Ah1[4], Al0[4], Al1[4];
  #pragma unroll
  for (int rs = 0; rs < 4; ++rs) {
    size_t ab = (size_t)(rb * 4 + rs) * 1024 + lofs;
    Ah0[rs] = *(const bf16x8*)(Ah + ab);
    Ah1[rs] = *(const bf16x8*)(Ah + ab + 512);
    Al0[rs] = *(const bf16x8*)(Al + ab);
    Al1[rs] = *(const bf16x8*)(Al + ab + 512);
  }

  // online-LSE state: 16 (m,s) pairs (4 sets x 4 sub-rows), base-2 log domain
  float sm[16], ss[16];
  #pragma unroll
  for (int i = 0; i < 16; ++i) { sm[i] = NEGINF; ss[i] = 0.0f; }

  // wave owns 16 col-tiles = 8 pairs; wave-uniform base pointers (saddr loads)
  const __bf16* pbh = Bh + (size_t)wave * 16 * 1024;
  const __bf16* pbl = Bl + (size_t)wave * 16 * 1024;
  int hb0 = wave * 256;

  // prefetch tile-pair 0
  bf16x8 c0h0 = *(const bf16x8*)(pbh + lofs);
  bf16x8 c0h1 = *(const bf16x8*)(pbh + lofs + 512);
  bf16x8 c0l0 = *(const bf16x8*)(pbl + lofs);
  bf16x8 c0l1 = *(const bf16x8*)(pbl + lofs + 512);
  bf16x8 c1h0 = *(const bf16x8*)(pbh + lofs + 1024);
  bf16x8 c1h1 = *(const bf16x8*)(pbh + lofs + 1536);
  bf16x8 c1l0 = *(const bf16x8*)(pbl + lofs + 1024);
  bf16x8 c1l1 = *(const bf16x8*)(pbl + lofs + 1536);

  #pragma unroll 1
  for (int tp = 0; tp < 8; ++tp) {
    // issue next pair's loads first (stay in flight across this pair's MFMA)
    int bump = (tp < 7) ? 2048 : 0;
    pbh += bump; pbl += bump;
    bf16x8 n0h0 = *(const bf16x8*)(pbh + lofs);
    bf16x8 n0h1 = *(const bf16x8*)(pbh + lofs + 512);
    bf16x8 n0l0 = *(const bf16x8*)(pbl + lofs);
    bf16x8 n0l1 = *(const bf16x8*)(pbl + lofs + 512);
    bf16x8 n1h0 = *(const bf16x8*)(pbh + lofs + 1024);
    bf16x8 n1h1 = *(const bf16x8*)(pbh + lofs + 1536);
    bf16x8 n1l0 = *(const bf16x8*)(pbl + lofs + 1024);
    bf16x8 n1l1 = *(const bf16x8*)(pbl + lofs + 1536);
    float hp0 = hlds[hb0 + tp * 32 + mrow] - inv_eps2;
    float hp1 = hlds[hb0 + tp * 32 + 16 + mrow] - inv_eps2;

    #pragma unroll
    for (int rs = 0; rs < 4; ++rs) {
      f32x4 acc0 = {0.0f, 0.0f, 0.0f, 0.0f};
      acc0 = mfma16(Ah0[rs], c0h0, acc0);
      acc0 = mfma16(Ah1[rs], c0h1, acc0);
      acc0 = mfma16(Al0[rs], c0h0, acc0);
      acc0 = mfma16(Al1[rs], c0h1, acc0);
      acc0 = mfma16(Ah0[rs], c0l0, acc0);
      acc0 = mfma16(Ah1[rs], c0l1, acc0);
      f32x4 acc1 = {0.0f, 0.0f, 0.0f, 0.0f};
      acc1 = mfma16(Ah0[rs], c1h0, acc1);
      acc1 = mfma16(Ah1[rs], c1h1, acc1);
      acc1 = mfma16(Al0[rs], c1h0, acc1);
      acc1 = mfma16(Al1[rs], c1h1, acc1);
      acc1 = mfma16(Ah0[rs], c1l0, acc1);
      acc1 = mfma16(Ah1[rs], c1l1, acc1);
      #pragma unroll
      for (int q = 0; q < 4; ++q) {
        int id = rs * 4 + q;
        float tv0 = fmaf(fminf(acc0[q], 1.0f), inv_eps2, hp0);
        float tv1 = fmaf(fminf(acc1[q], 1.0f), inv_eps2, hp1);
        float mn = fmaxf(sm[id], fmaxf(tv0, tv1));
        ss[id] = fmaf(ss[id], exp2v(sm[id] - mn),
                      exp2v(tv0 - mn) + exp2v(tv1 - mn));
        sm[id] = mn;
      }
    }
    c0h0 = n0h0; c0h1 = n0h1; c0l0 = n0l0; c0l1 = n0l1;
    c1h0 = n1h0; c1h1 = n1h1; c1l0 = n1l0; c1l1 = n1l1;
  }

  // merge (m,s) across the 16 col-lanes of each quad group
  #pragma unroll
  for (int o = 1; o < 16; o <<= 1) {
    #pragma unroll
    for (int i = 0; i < 16; ++i) {
      float m2 = __shfl_xor(sm[i], o, 64);
      float s2 = __shfl_xor(ss[i], o, 64);
      float mn = fmaxf(sm[i], m2);
      ss[i] = ss[i] * exp2v(sm[i] - mn) + s2 * exp2v(m2 - mn);
      sm[i] = mn;
    }
  }

  // per-wave partials -> LDS (row within block = rs*16 + quad*4 + q)
  if (mrow == 0) {
    #pragma unroll
    for (int rs = 0; rs < 4; ++rs)
      #pragma unroll
      for (int q = 0; q < 4; ++q) {
        int row = rs * 16 + quad * 4 + q;
        mred[wave][row] = sm[rs * 4 + q];
        sred[wave][row] = ss[rs * 4 + q];
      }
  }
  __syncthreads();

  // merge 16 waves (disjoint col ranges), finalize, write potential
  if (threadIdx.x < 64) {
    int row = threadIdx.x;
    float m = mred[0][row], s = sred[0][row];
    #pragma unroll
    for (int w = 1; w < 16; ++w) {
      float m2 = mred[w][row], s2 = sred[w][row];
      float mn = fmaxf(m, m2);
      s = s * exp2v(m - mn) + s2 * exp2v(m2 - mn);
      m = mn;
    }
    float ft = -epsl2 * (m + log2v(s));
    float v = avg ? 0.5f * (potOld[(size_t)mat * NPTS + i0 + row] + ft) : ft;
    potNew[(size_t)mat * NPTS + i0 + row] = v;
  }
}

// ---------------------------------------------------------------------------
// out = mean(f_ba - f_aa) + mean(g_ab - g_bb), potentials at pot[0..3][NPTS]
// ---------------------------------------------------------------------------
__global__ __launch_bounds__(256) void final_kernel(
    const float* __restrict__ pot, float* __restrict__ out) {
  __shared__ float red[256];
  float s = 0.0f;
  for (int j = threadIdx.x; j < NPTS; j += 256)
    s += (pot[j] - pot[2 * NPTS + j]) + (pot[NPTS + j] - pot[3 * NPTS + j]);
  red[threadIdx.x] = s;
  __syncthreads();
  #pragma unroll
  for (int o = 128; o; o >>= 1) {
    if (threadIdx.x < o) red[threadIdx.x] += red[threadIdx.x + o];
    __syncthreads();
  }
  if (threadIdx.x == 0) out[0] = red[0] / (float)NPTS;
}

extern "C" void kernel_launch(void* const* d_in, const int* in_sizes, int n_in,
                              void* d_out, int out_size, void* d_ws, size_t ws_size,
                              hipStream_t stream) {
  const float* x = (const float*)d_in[0];
  const float* y = (const float*)d_in[1];
  char* ws = (char*)d_ws;

  // workspace layout (~2.2 MB): fragment-packed hi/lo matrices + potentials
  __bf16* xhf = (__bf16*)ws;
  __bf16* xlf = xhf + (size_t)NPTS * DIM;
  __bf16* yhf = xlf + (size_t)NPTS * DIM;
  __bf16* ylf = yhf + (size_t)NPTS * DIM;
  float* potA = (float*)(ylf + (size_t)NPTS * DIM);   // 4 * NPTS
  float* potB = potA + 4 * (size_t)NPTS;
  size_t needed = (size_t)((char*)(potB + 4 * (size_t)NPTS) - ws);
  if (ws_size < needed) return;

  norm_repack_kernel<<<256, 256, 0, stream>>>(x, y, xhf, xlf, yhf, ylf);

  // geomloss epsilon schedule (p=2, blur=0.05, scaling=0.8, diameter=2)
  double lst[32];
  int c = 0;
  lst[c++] = 4.0;
  double start = 2.0 * log(2.0), stop = 2.0 * log(0.05), step = 2.0 * log(0.8);
  for (int k = 0;; ++k) {
    double v = start + (double)k * step;
    if (v <= stop) break;
    lst[c++] = exp(v);
  }
  lst[c++] = 0.05 * 0.05;   // c == 19

  const double LOG2E = 1.4426950408889634074;
  const double LN2   = 0.6931471805599453094;

  // sweeps: p=0 init (no pot, assign); p=1..c loop (avg); p=c+1 final (assign)
  for (int p = 0; p < c + 2; ++p) {
    double e = (p == 0) ? lst[0] : ((p <= c) ? lst[p - 1] : lst[c - 1]);
    float inv_eps2 = (float)(LOG2E / e);   // log2(e)/eps
    float epsl2    = (float)(e * LN2);     // eps*ln(2)
    int use_pot = (p > 0) ? 1 : 0;
    int avg = (p >= 1 && p <= c) ? 1 : 0;
    const float* po = (p & 1) ? potB : potA;
    float* pn       = (p & 1) ? potA : potB;
    fused_pass_kernel<<<256, 1024, 0, stream>>>(xhf, xlf, yhf, ylf, po, pn,
                                                inv_eps2, epsl2, use_pot, avg);
  }
  // c+2 = 21 sweeps; last sweep (p=20, even) wrote potB
  final_kernel<<<1, 256, 0, stream>>>(potB, (float*)d_out);
}